// Round 13
// baseline (392.641 us; speedup 1.0000x reference)
//
#include <hip/hip_runtime.h>
#include <cmath>

// x [B=4096][T=512][D=4], H=32, gates 4H=128 (PyTorch order i,f,g,o).
constexpr int T   = 512;
constexpr int D   = 4;
constexpr int H   = 32;
constexpr int BT  = 16;    // batch cols per block
constexpr int BLK = 128;   // 2 waves: wave0 = layer0, wave1 = layer1
constexpr int LAG = 8;     // L2 time lag == barrier interval
constexpr int NS  = 16;    // h0 ring slots (= 2*LAG)

constexpr float LOG2E     = 1.44269504088896340736f;
constexpr float NEG2LOG2E = -2.88539008177792681472f;

// x staged as FULL zero-padded B-fragments (8 shorts/t). Col stride 4104
// shorts = 2052 dwords ≡ 4 (mod 32): broadcast b128 reads 2-way = free.
constexpr int XSTRIDE = 4104;
// h0 ring col stride 36 shorts = 18 dwords: b128 lane starts 18*nl+4q mod 32
// spread over 16 distinct banks, max 2-way overlap = free.
constexpr int RSTR = 36;

typedef short bf8 __attribute__((ext_vector_type(8)));  // 8 bf16 (4 VGPRs)
typedef float f4  __attribute__((ext_vector_type(4)));  // MFMA C/D

// fp32 -> bf16 round-to-nearest-even (staging/weights)
static __device__ __forceinline__ short bf16_rtn(float v) {
    unsigned u = __float_as_uint(v);
    u += 0x7FFFu + ((u >> 16) & 1u);
    return (short)(u >> 16);
}

// R22 (resubmit x4 — R10/R11/R12 benches were broker timeouts, no data):
// REGISTER-LOCAL recurrence via k-permutation of the h-side weights.
// pi(q,j) = (j<4 ? 4q+j : 16+4q+j-4): W_hh* columns are stored permuted so
// the MFMA D/act output of lane (q,nl) — units {4q..4q+3, 16+4q..16+4q+3},
// col nl — IS its next-step B-fragment (k=8q+j <-> unit pi(q,j)). The
// h recurrence never touches LDS; no per-step barrier. 2 waves: L0 owns all
// of layer0 (8 tiles x 2-chain = 16 MFMA/step, 2x actquad), L2 lags LAG=8
// behind via the R19-proven h0 ring (pi-packed b128 slots, barrier /8 steps).
// x: R15-proven LDS staging, prefetched 1 step ahead; ring reads likewise.
// All pieces individually proven passing (R15-17 staging, R19 ring/lag,
// R21 actquad); pi is a static k-relabel.
__global__ __launch_bounds__(BLK, 1) void lstm_pi(
    const float* __restrict__ x,
    const float* __restrict__ W_ih0, const float* __restrict__ W_hh0,
    const float* __restrict__ b_ih0, const float* __restrict__ b_hh0,
    const float* __restrict__ W_ih1, const float* __restrict__ W_hh1,
    const float* __restrict__ b_ih1, const float* __restrict__ b_hh1,
    const float* __restrict__ W_out, const float* __restrict__ b_out,
    float* __restrict__ out)
{
    __shared__ __align__(16) short xbf[16 * XSTRIDE];   // 128.3 KiB x frags
    __shared__ __align__(16) short h0r[NS][16][RSTR];   // 18 KiB h0 ring (pi-packed)
    __shared__ __align__(16) float h1f[16][36];         // final h1 fp32 for head

    const int tid  = threadIdx.x;
    const int isL0 = (tid < 64);       // wave 0 = layer 0
    const int lane = tid & 63;
    const int q    = lane >> 4;        // quad
    const int nl   = lane & 15;        // batch col
    const int b0   = blockIdx.x * BT;

    // ---- stage x -> zero-padded bf16 fragments (R15-proven path) ----
    for (int idx = tid; idx < 16 * T; idx += BLK) {
        const int col = idx & 15;
        const int t   = idx >> 4;
        float4 xv = *(const float4*)(x + ((size_t)(b0 + col) * T + t) * D);
        bf8 v = {0, 0, 0, 0, 0, 0, 0, 0};
        v[0] = bf16_rtn(xv.x); v[1] = bf16_rtn(xv.y);
        v[2] = bf16_rtn(xv.z); v[3] = bf16_rtn(xv.w);
        *(bf8*)&xbf[col * XSTRIDE + t * 8] = v;
    }

    // ---- weights: tile (g,hf) rows = 32g+16hf+nl. h-side k PERMUTED by pi.
    // w1 = cross-fresh operand (L0: W_hh0 vs h0(t-1)reg; L2: W_ih1 vs ring);
    // w2 = other (L0: W_ih0 vs x, K-padded, NO pi; L2: W_hh1 vs h1reg, pi).
    const float* W1 = isL0 ? W_hh0 : W_ih1;
    bf8 w1[4][2], w2[4][2];
    f4  bias[4][2];
    #pragma unroll
    for (int g = 0; g < 4; ++g) {
        const float sc = (g == 2) ? NEG2LOG2E : -LOG2E;
        #pragma unroll
        for (int hf = 0; hf < 2; ++hf) {
            const int row = 32 * g + 16 * hf + nl;
            #pragma unroll
            for (int j = 0; j < 8; ++j) {
                const int kk = (j < 4) ? (4 * q + j) : (16 + 4 * q + (j - 4)); // pi
                w1[g][hf][j] = bf16_rtn(W1[row * H + kk] * sc);
                float v2 = isL0 ? ((q == 0 && j < 4) ? W_ih0[row * D + j] : 0.0f)
                                : W_hh1[row * H + kk];
                w2[g][hf][j] = bf16_rtn(v2 * sc);
            }
            #pragma unroll
            for (int r = 0; r < 4; ++r) {
                const int gr = 32 * g + 16 * hf + 4 * q + r;
                bias[g][hf][r] = sc * (isL0 ? (b_ih0[gr] + b_hh0[gr])
                                            : (b_ih1[gr] + b_hh1[gr]));
            }
        }
    }

    // cell state: cs0 = units 4q..4q+3, cs1 = units 16+4q..16+4q+3 (col nl)
    f4 cs0 = {0.0f, 0.0f, 0.0f, 0.0f};
    f4 cs1 = {0.0f, 0.0f, 0.0f, 0.0f};
    // own-h fragment (pi-packed): L0 = h0(t-1), L2 = h1(jj-1); h(-1)=0
    bf8 hreg = {0, 0, 0, 0, 0, 0, 0, 0};

    const short* xcol = &xbf[nl * XSTRIDE];

    __syncthreads();

    bf8 bx = *(const bf8*)&xcol[0];    // x(0) preload (L0)
    bf8 rb1;                            // L2 ring prefetch register

    // ---- act for 4 units (R21's 4-way-merged-rcp version, proven) ----
    auto actquad = [&](f4& c4, const f4 zi, const f4 zf, const f4 zg, const f4 zo,
                       unsigned& pk0, unsigned& pk1, f4& hv) {
        f4 ei, ef, eg, eo, ec;
        #pragma unroll
        for (int e = 0; e < 4; ++e) {
            ei[e] = __builtin_amdgcn_exp2f(zi[e]);
            ef[e] = __builtin_amdgcn_exp2f(zf[e]);
            eg[e] = __builtin_amdgcn_exp2f(zg[e]);
            eo[e] = __builtin_amdgcn_exp2f(zo[e]);
        }
        f4 D1 = 1.0f + ef;
        f4 D2 = (1.0f + ei) * (1.0f + eg);
        f4 Dm = D1 * D2;
        float s0 = Dm[0] * Dm[1], s1 = Dm[2] * Dm[3];
        float R  = __builtin_amdgcn_rcpf(s0 * s1);
        float t0 = R * s1, t1 = R * s0;
        f4 inv;
        inv[0] = t0 * Dm[1]; inv[1] = t0 * Dm[0];
        inv[2] = t1 * Dm[3]; inv[3] = t1 * Dm[2];
        c4 = (c4 * D2 + (1.0f - eg) * D1) * inv;
        #pragma unroll
        for (int e = 0; e < 4; ++e)
            ec[e] = __builtin_amdgcn_exp2f(c4[e] * NEG2LOG2E);
        f4 Do = (1.0f + eo) * (1.0f + ec);
        float u0 = Do[0] * Do[1], u1 = Do[2] * Do[3];
        float Q  = __builtin_amdgcn_rcpf(u0 * u1);
        float v0 = Q * u1, v1 = Q * u0;
        f4 invo;
        invo[0] = v0 * Do[1]; invo[1] = v0 * Do[0];
        invo[2] = v1 * Do[3]; invo[3] = v1 * Do[2];
        hv = (1.0f - ec) * invo;
        asm("v_cvt_pk_bf16_f32 %0, %1, %2" : "=v"(pk0) : "v"(hv[0]), "v"(hv[1]));
        asm("v_cvt_pk_bf16_f32 %0, %1, %2" : "=v"(pk1) : "v"(hv[2]), "v"(hv[3]));
    };

    // ---- one 8-step group; barrier at end. sbase = (t0/8 & 1)*8. ----
    auto group8 = [&](const int t0, const int sbase, const bool do0, const bool do1) {
        if (do0 && isL0) {
            #pragma unroll
            for (int u = 0; u < 8; ++u) {
                bf8 b2 = bx;
                bx = *(const bf8*)&xcol[((t0 + u + 1) & (T - 1)) * 8]; // next x
                f4 acc[4][2];
                #pragma unroll
                for (int g = 0; g < 4; ++g)
                    #pragma unroll
                    for (int hf = 0; hf < 2; ++hf) {
                        f4 A = __builtin_amdgcn_mfma_f32_16x16x32_bf16(w2[g][hf], b2, bias[g][hf], 0, 0, 0);
                        acc[g][hf] = __builtin_amdgcn_mfma_f32_16x16x32_bf16(w1[g][hf], hreg, A, 0, 0, 0);
                    }
                unsigned pka, pkb, pkc, pkd; f4 hv;
                actquad(cs0, acc[0][0], acc[1][0], acc[2][0], acc[3][0], pka, pkb, hv);
                actquad(cs1, acc[0][1], acc[1][1], acc[2][1], acc[3][1], pkc, pkd, hv);
                int4 pkv; pkv.x = (int)pka; pkv.y = (int)pkb; pkv.z = (int)pkc; pkv.w = (int)pkd;
                hreg = __builtin_bit_cast(bf8, pkv);           // h0(t) pi-frag
                *(bf8*)&h0r[sbase + u][nl][8 * q] = hreg;      // ring, off-chain
            }
        }
        if (do1 && !isL0) {
            // u=0 slot (written by L0 last group; visible post-barrier)
            rb1 = *(const bf8*)&h0r[(sbase + 8) & (NS - 1)][nl][8 * q];
            #pragma unroll
            for (int u = 0; u < 8; ++u) {
                bf8 b1 = rb1;
                if (u < 7)
                    rb1 = *(const bf8*)&h0r[(sbase + u + 9) & (NS - 1)][nl][8 * q];
                f4 acc[4][2];
                #pragma unroll
                for (int g = 0; g < 4; ++g)
                    #pragma unroll
                    for (int hf = 0; hf < 2; ++hf) {
                        f4 A = __builtin_amdgcn_mfma_f32_16x16x32_bf16(w2[g][hf], hreg, bias[g][hf], 0, 0, 0);
                        acc[g][hf] = __builtin_amdgcn_mfma_f32_16x16x32_bf16(w1[g][hf], b1, A, 0, 0, 0);
                    }
                unsigned pka, pkb, pkc, pkd; f4 hv0, hv1;
                actquad(cs0, acc[0][0], acc[1][0], acc[2][0], acc[3][0], pka, pkb, hv0);
                actquad(cs1, acc[0][1], acc[1][1], acc[2][1], acc[3][1], pkc, pkd, hv1);
                int4 pkv; pkv.x = (int)pka; pkv.y = (int)pkb; pkv.z = (int)pkc; pkv.w = (int)pkd;
                hreg = __builtin_bit_cast(bf8, pkv);           // h1(jj) pi-frag
                if (t0 + u - LAG == T - 1) {                   // head input
                    *(f4*)&h1f[nl][4 * q]      = hv0;
                    *(f4*)&h1f[nl][16 + 4 * q] = hv1;
                }
            }
        }
        __syncthreads();   // h0(t0..t0+7) visible to L2 next group
    };

    group8(0, 0, true, false);                 // t=0..7: L0 only
    #pragma unroll 1
    for (int g = 1; g < 64; ++g)
        group8(8 * g, (g & 1) * 8, true, true);
    group8(T, 0, false, true);                 // flush: L2 jj=504..511

    // ---- output head: out[b0+n] = b_out + W_out . h1(T-1) ----
    if (tid < BT) {
        float acc = b_out[0];
        #pragma unroll
        for (int u = 0; u < H; ++u) acc = fmaf(W_out[u], h1f[tid][u], acc);
        out[b0 + tid] = acc;
    }
}

extern "C" void kernel_launch(void* const* d_in, const int* in_sizes, int n_in,
                              void* d_out, int out_size, void* d_ws, size_t ws_size,
                              hipStream_t stream) {
    const float* x     = (const float*)d_in[0];
    const float* W_ih0 = (const float*)d_in[1];
    const float* W_hh0 = (const float*)d_in[2];
    const float* b_ih0 = (const float*)d_in[3];
    const float* b_hh0 = (const float*)d_in[4];
    const float* W_ih1 = (const float*)d_in[5];
    const float* W_hh1 = (const float*)d_in[6];
    const float* b_ih1 = (const float*)d_in[7];
    const float* b_hh1 = (const float*)d_in[8];
    const float* W_out = (const float*)d_in[9];
    const float* b_out = (const float*)d_in[10];
    float* out = (float*)d_out;

    const int B = out_size;          // 4096
    lstm_pi<<<B / BT, BLK, 0, stream>>>(x, W_ih0, W_hh0, b_ih0, b_hh0,
                                        W_ih1, W_hh1, b_ih1, b_hh1,
                                        W_out, b_out, out);
}

// Round 14
// 276.392 us; speedup vs baseline: 1.4206x; 1.4206x over previous
//
#include <hip/hip_runtime.h>
#include <cmath>

// x [B=4096][T=512][D=4], H=32, gates 4H=128 (PyTorch order i,f,g,o).
constexpr int T   = 512;
constexpr int D   = 4;
constexpr int H   = 32;
constexpr int BT  = 16;    // batch cols per block — ALL real
constexpr int BLK = 256;   // 4 waves: (layer, unit-half)

constexpr float LOG2E     = 1.44269504088896340736f;
constexpr float NEG2LOG2E = -2.88539008177792681472f;

// x staged as FULL zero-padded B-fragments (8 shorts/t). Col stride 4104
// shorts = 2052 dwords ≡ 4 (mod 32): the 16 per-iter broadcast b128 reads
// land 2-way per bank-quad (free). 16*4104*2B = 131.3 KB.
constexpr int XSTRIDE = 4104;
// h row stride 40 shorts = 20 dwords: b128 frag reads have bank-quad index
// (5*nl+q) mod 8 — exactly 2-way (nl vs nl+8) = free.
constexpr int HSTR = 40;

typedef short bf8 __attribute__((ext_vector_type(8)));  // 8 bf16 (4 VGPRs)
typedef float f4  __attribute__((ext_vector_type(4)));  // MFMA C/D
typedef float f2  __attribute__((ext_vector_type(2)));  // packed-f32 pair

// fp32 -> bf16 round-to-nearest-even (staging path)
static __device__ __forceinline__ short bf16_rtn(float v) {
    unsigned u = __float_as_uint(v);
    u += 0x7FFFu + ((u >> 16) & 1u);
    return (short)(u >> 16);
}

// R23 = R16 VERBATIM (session best: bench 277.356 µs, dispatch 217-222 µs).
// Revert executed per R22's pre-committed read (>240 µs). Structural record:
// R17 (2 waves/SIMD dup: null — barrier phase-lock), R18/R19/R22 (wave-/
// register-local recurrence: −50-70% — act issue concentrates on 2 SIMDs),
// R20 (chain cuts: −17%), R21 (trans merge: −2%). The 4-wave (layer,
// unit-half) topology is the unique full-occupancy act-distribution; step
// = 512 x ~1030 cy serial-recurrence floor, not HBM/MFMA-bound.
__global__ __launch_bounds__(BLK, 1) void lstm_bf16p(
    const float* __restrict__ x,
    const float* __restrict__ W_ih0, const float* __restrict__ W_hh0,
    const float* __restrict__ b_ih0, const float* __restrict__ b_hh0,
    const float* __restrict__ W_ih1, const float* __restrict__ W_hh1,
    const float* __restrict__ b_ih1, const float* __restrict__ b_hh1,
    const float* __restrict__ W_out, const float* __restrict__ b_out,
    float* __restrict__ out)
{
    __shared__ __align__(16) short xbf[16 * XSTRIDE];   // 131.3 KB staged x frags
    __shared__ __align__(16) short h0b[2][16][HSTR];    // h, [buf][col][unit]
    __shared__ __align__(16) short h1b[2][16][HSTR];
    __shared__ __align__(16) float h1f[16][36];         // final h1 fp32 for the head

    const int tid   = threadIdx.x;
    const int w     = tid >> 6;
    const int lane  = tid & 63;
    const int q     = lane >> 4;       // quad
    const int nl    = lane & 15;       // batch col (all real)
    const int layer = w >> 1;          // 0: L1, 1: L2
    const int ug    = (w & 1) << 4;    // unit group offset 0 / 16
    const int b0    = blockIdx.x * BT;

    // ---- stage x -> zero-padded bf16 fragments ----
    for (int idx = tid; idx < 16 * T; idx += BLK) {
        const int col = idx & 15;
        const int t   = idx >> 4;
        float4 xv = *(const float4*)(x + ((size_t)(b0 + col) * T + t) * D);
        bf8 v = {0, 0, 0, 0, 0, 0, 0, 0};
        v[0] = bf16_rtn(xv.x); v[1] = bf16_rtn(xv.y);
        v[2] = bf16_rtn(xv.z); v[3] = bf16_rtn(xv.w);
        *(bf8*)&xbf[col * XSTRIDE + t * 8] = v;
    }
    // zero both h buffers
    for (int idx = tid; idx < 2 * 16 * HSTR; idx += BLK) {
        (&h0b[0][0][0])[idx] = 0;
        (&h1b[0][0][0])[idx] = 0;
    }

    // ---- weights: tile g = gate type. A-frag row = 32g + ug + nl, k = 8q+j.
    const float* W1 = layer ? W_ih1 : W_hh0;
    bf8 w1[4], w2[4];
    f4  bias[4];
    #pragma unroll
    for (int g = 0; g < 4; ++g) {
        const float sc = (g == 2) ? NEG2LOG2E : -LOG2E;
        const int row = 32 * g + ug + nl;
        #pragma unroll
        for (int j = 0; j < 8; ++j) {
            w1[g][j] = bf16_rtn(W1[row * H + 8 * q + j] * sc);
            float v2 = layer ? W_hh1[row * H + 8 * q + j]
                             : ((q == 0 && j < 4) ? W_ih0[row * D + j] : 0.0f);
            w2[g][j] = bf16_rtn(v2 * sc);
        }
        #pragma unroll
        for (int r = 0; r < 4; ++r) {
            const int gr = 32 * g + ug + 4 * q + r;
            bias[g][r] = sc * (layer ? (b_ih1[gr] + b_hh1[gr])
                                     : (b_ih0[gr] + b_hh0[gr]));
        }
    }

    // cell state, fp32, lane-local — carried as two packed pairs (r01, r23)
    f2 cA; cA.x = 0.0f; cA.y = 0.0f;
    f2 cB; cB.x = 0.0f; cB.y = 0.0f;

    const short* xcol = &xbf[nl * XSTRIDE];

    __syncthreads();

    // ---- packed activation for one r-pair ----
    // acc components pre-scaled: -log2e*z (i,f,o) / -2log2e*z (g).
    // c' = c/(1+ef) + (1-eg)/((1+ei)(1+eg));  h = (1-ec)/((1+eo)(1+ec)).
    // One rcp per pair per site via R=rcp(a*b) -> 1/a = R*b, 1/b = R*a.
    auto actpair = [&](f2& c2, float zi0, float zi1, float zf0, float zf1,
                       float zg0, float zg1, float zo0, float zo1,
                       unsigned& pkd, f2& hv) {
        f2 ei, ef, eg, eo, ec;
        ei.x = __builtin_amdgcn_exp2f(zi0); ei.y = __builtin_amdgcn_exp2f(zi1);
        ef.x = __builtin_amdgcn_exp2f(zf0); ef.y = __builtin_amdgcn_exp2f(zf1);
        eg.x = __builtin_amdgcn_exp2f(zg0); eg.y = __builtin_amdgcn_exp2f(zg1);
        eo.x = __builtin_amdgcn_exp2f(zo0); eo.y = __builtin_amdgcn_exp2f(zo1);
        f2 D1 = 1.0f + ef;
        f2 D2 = (1.0f + ei) * (1.0f + eg);
        f2 Dm = D1 * D2;
        float R = __builtin_amdgcn_rcpf(Dm.x * Dm.y);
        f2 rD; rD.x = R * Dm.y; rD.y = R * Dm.x;
        c2 = (c2 * D2 + (1.0f - eg) * D1) * rD;
        ec.x = __builtin_amdgcn_exp2f(c2.x * NEG2LOG2E);
        ec.y = __builtin_amdgcn_exp2f(c2.y * NEG2LOG2E);
        f2 Do = (1.0f + eo) * (1.0f + ec);
        float Ro = __builtin_amdgcn_rcpf(Do.x * Do.y);
        f2 ro; ro.x = Ro * Do.y; ro.y = Ro * Do.x;
        hv = (1.0f - ec) * ro;
        // dword = [bf16(hv.y) | bf16(hv.x)] — RNE pack, 1 instr
        asm("v_cvt_pk_bf16_f32 %0, %1, %2" : "=v"(pkd) : "v"(hv.x), "v"(hv.y));
    };

    // ---- one timestep; rb/wb are compile-time literals at each call site ----
    auto body = [&](const int i, const int rb, const int wb) {
        // issue all DS reads first
        bf8 b2;
        if (layer == 0) {   // x(i) fragment, pre-padded (i=T reads t=0, unused)
            b2 = *(const bf8*)&xcol[(i & (T - 1)) * 8];
        } else {            // h1(i-2)
            b2 = *(const bf8*)&h1b[rb][nl][8 * q];
        }
        bf8 b1 = *(const bf8*)&h0b[rb][nl][8 * q];              // h0(i-1)

        // ---- 8 MFMAs: 4 gate tiles x 2-chain (C starts at scaled bias) ----
        f4 acc[4];
        #pragma unroll
        for (int g = 0; g < 4; ++g) {
            f4 A = __builtin_amdgcn_mfma_f32_16x16x32_bf16(w2[g], b2, bias[g], 0, 0, 0);
            A    = __builtin_amdgcn_mfma_f32_16x16x32_bf16(w1[g], b1, A,       0, 0, 0);
            acc[g] = A;
        }

        // ---- lane-local state update: units ug+4q+r, col nl ----
        const bool act = layer ? (i >= 1) : (i < T);
        if (act) {
            unsigned pk0, pk1;
            f2 hvA, hvB;
            actpair(cA, acc[0][0], acc[0][1], acc[1][0], acc[1][1],
                        acc[2][0], acc[2][1], acc[3][0], acc[3][1], pk0, hvA);
            actpair(cB, acc[0][2], acc[0][3], acc[1][2], acc[1][3],
                        acc[2][2], acc[2][3], acc[3][2], acc[3][3], pk1, hvB);
            int2 hh; hh.x = (int)pk0; hh.y = (int)pk1;
            if (layer == 0) {
                *(int2*)&h0b[wb][nl][ug + 4 * q] = hh;
            } else {
                *(int2*)&h1b[wb][nl][ug + 4 * q] = hh;
                if (i == T) {   // h1(T-1), fp32, for the output head
                    float4 hw;
                    hw.x = hvA.x; hw.y = hvA.y; hw.z = hvB.x; hw.w = hvB.y;
                    *(float4*)&h1f[nl][ug + 4 * q] = hw;
                }
            }
        }
        __syncthreads();   // buffer wb becomes rb of the next step
    };

    #pragma unroll 1
    for (int i = 0; i < T; i += 2) {   // pairs (even: rb=0, odd: rb=1)
        body(i,     0, 1);
        body(i + 1, 1, 0);
    }
    body(T, 0, 1);                     // i = 512 (flush L2 step 511)

    // ---- output head: out[b0+n] = b_out + W_out . h1(T-1) ----
    if (tid < BT) {
        float acc = b_out[0];
        #pragma unroll
        for (int u = 0; u < H; ++u) acc = fmaf(W_out[u], h1f[tid][u], acc);
        out[b0 + tid] = acc;
    }
}

extern "C" void kernel_launch(void* const* d_in, const int* in_sizes, int n_in,
                              void* d_out, int out_size, void* d_ws, size_t ws_size,
                              hipStream_t stream) {
    const float* x     = (const float*)d_in[0];
    const float* W_ih0 = (const float*)d_in[1];
    const float* W_hh0 = (const float*)d_in[2];
    const float* b_ih0 = (const float*)d_in[3];
    const float* b_hh0 = (const float*)d_in[4];
    const float* W_ih1 = (const float*)d_in[5];
    const float* W_hh1 = (const float*)d_in[6];
    const float* b_ih1 = (const float*)d_in[7];
    const float* b_hh1 = (const float*)d_in[8];
    const float* W_out = (const float*)d_in[9];
    const float* b_out = (const float*)d_in[10];
    float* out = (float*)d_out;

    const int B = out_size;          // 4096
    lstm_bf16p<<<B / BT, BLK, 0, stream>>>(x, W_ih0, W_hh0, b_ih0, b_hh0,
                                           W_ih1, W_hh1, b_ih1, b_hh1,
                                           W_out, b_out, out);
}